// Round 12
// baseline (193.894 us; speedup 1.0000x reference)
//
#include <hip/hip_runtime.h>
#include <hip/hip_bf16.h>

#define T_TOK 2048
#define E_DIM 512
#define NHEAD 8
#define DHEAD 64
#define HID_D 2048
#define NEXP 4
#define NROW_ (2 * T_TOK)
#define VT_STRIDE 4608

typedef short short8 __attribute__((ext_vector_type(8)));
typedef float floatx4 __attribute__((ext_vector_type(4)));

__device__ __forceinline__ void gld16(const void* g, void* l) {
  __builtin_amdgcn_global_load_lds((const __attribute__((address_space(1))) void*)g,
                                   (__attribute__((address_space(3))) void*)l, 16, 0, 0);
}

__device__ inline float wave_sum(float v) {
  for (int off = 32; off > 0; off >>= 1) v += __shfl_xor(v, off);
  return v;
}

__device__ __forceinline__ unsigned pack_bf2(float a, float b) {
  __hip_bfloat16 ha = __float2bfloat16(a), hb = __float2bfloat16(b);
  unsigned ua = *(unsigned short*)&ha, ub = *(unsigned short*)&hb;
  return ua | (ub << 16);
}

__device__ __forceinline__ void cvt4(const float* __restrict__ s, __hip_bfloat16* __restrict__ d,
                                     int i4, int n) {
  if (i4 < n) {
    float4 v = *reinterpret_cast<const float4*>(s + i4);
    __hip_bfloat16 tmp[4] = {__float2bfloat16(v.x), __float2bfloat16(v.y),
                             __float2bfloat16(v.z), __float2bfloat16(v.w)};
    *reinterpret_cast<ushort4*>(d + i4) = *reinterpret_cast<const ushort4*>(tmp);
  }
}

__global__ void cvt_weights(const float* __restrict__ s0, const float* __restrict__ s1,
                            const float* __restrict__ s2, const float* __restrict__ s3,
                            __hip_bfloat16* d0, __hip_bfloat16* d1,
                            __hip_bfloat16* d2, __hip_bfloat16* d3,
                            int n0, int n1, int n2, int n3) {
  int i4 = (blockIdx.x * 256 + threadIdx.x) * 4;
  cvt4(s0, d0, i4, n0);
  cvt4(s1, d1, i4, n1);
  cvt4(s2, d2, i4, n2);
  cvt4(s3, d3, i4, n3);
}

// one wave per token: 4 gate dots, top-2, softmax probs
__global__ void gate_kernel(const float* __restrict__ x, const float* __restrict__ gw,
                            const float* __restrict__ gb, int* token_e, float* token_p) {
  int wid = threadIdx.x >> 6, lane = threadIdx.x & 63;
  int t = blockIdx.x * 4 + wid;
  float a0 = 0, a1 = 0, a2 = 0, a3 = 0;
  for (int i = 0; i < 8; i++) {
    int c = lane + 64 * i;
    float xv = x[(size_t)t * E_DIM + c];
    a0 += xv * gw[0 * E_DIM + c];
    a1 += xv * gw[1 * E_DIM + c];
    a2 += xv * gw[2 * E_DIM + c];
    a3 += xv * gw[3 * E_DIM + c];
  }
  a0 = wave_sum(a0); a1 = wave_sum(a1); a2 = wave_sum(a2); a3 = wave_sum(a3);
  if (lane == 0) {
    float lg[4] = {a0 + gb[0], a1 + gb[1], a2 + gb[2], a3 + gb[3]};
    int i0 = 0;
    for (int e = 1; e < 4; e++) if (lg[e] > lg[i0]) i0 = e;   // strict > : lowest idx on tie
    int i1 = -1;
    for (int e = 0; e < 4; e++) {
      if (e == i0) continue;
      if (i1 < 0 || lg[e] > lg[i1]) i1 = e;
    }
    float e1 = __expf(lg[i1] - lg[i0]);
    float inv = 1.f / (1.f + e1);
    token_e[t] = i0; token_e[T_TOK + t] = i1;
    token_p[t] = inv; token_p[T_TOK + t] = e1 * inv;
  }
}

// fused count + prefix + stable compaction (8 blocks; each recomputes all counts)
__global__ void route_kernel(const int* __restrict__ token_e, int* perm, int* rowg,
                             int* pmap, int* invrow, int* offs_out, int* padoffs_out) {
  int g = blockIdx.x, kk = g >> 2, e = g & 3;
  int tid = threadIdx.x, wid = tid >> 6, lane = tid & 63;
  __shared__ int cnt_s[8][4];
  for (int gg = 0; gg < 8; gg++) {
    int kk2 = gg >> 2, e2 = gg & 3;
    int c = 0;
    for (int t = tid; t < T_TOK; t += 256) c += (token_e[kk2 * T_TOK + t] == e2);
    for (int off = 32; off; off >>= 1) c += __shfl_xor(c, off);
    if (lane == 0) cnt_s[gg][wid] = c;
  }
  __syncthreads();
  int offs[9], padoffs[9];
  offs[0] = 0; padoffs[0] = 0;
  for (int gg = 0; gg < 8; gg++) {
    int c = cnt_s[gg][0] + cnt_s[gg][1] + cnt_s[gg][2] + cnt_s[gg][3];
    offs[gg + 1] = offs[gg] + c;
    padoffs[gg + 1] = padoffs[gg] + ((c + 63) & ~63);
  }
  if (g == 0 && tid < 9) { offs_out[tid] = offs[tid]; padoffs_out[tid] = padoffs[tid]; }
  int og = offs[g], pg = padoffs[g];
  __shared__ int wcnt[4];
  __shared__ int base;
  if (tid == 0) base = 0;
  __syncthreads();
  for (int t0 = 0; t0 < T_TOK; t0 += 256) {
    int t = t0 + tid;
    bool pred = token_e[kk * T_TOK + t] == e;
    unsigned long long mask = __ballot(pred);
    int rank = __popcll(mask & ((1ull << lane) - 1ull));
    if (lane == 0) wcnt[wid] = __popcll(mask);
    __syncthreads();
    int woff = 0;
    for (int i = 0; i < wid; i++) woff += wcnt[i];
    if (pred) {
      int row = og + base + woff + rank;
      perm[row] = t;
      rowg[row] = g;
      pmap[row] = pg + (row - og);
      invrow[kk * T_TOK + t] = row;
    }
    __syncthreads();
    if (tid == 0) base += wcnt[0] + wcnt[1] + wcnt[2] + wcnt[3];
    __syncthreads();
  }
}

// one wave per row: LayerNorm -> bf16.  perm==nullptr: src row-indexed.
__global__ void ln_kernel(const float* __restrict__ src, const int* __restrict__ perm,
                          const int* __restrict__ rowg, const float* __restrict__ lnw,
                          const float* __restrict__ lnb, __hip_bfloat16* __restrict__ dst) {
  int wid = threadIdx.x >> 6, lane = threadIdx.x & 63;
  int row = blockIdx.x * 4 + wid;
  int e = rowg[row] & 3;
  const float* xr = src + (size_t)(perm ? perm[row] : row) * E_DIM;
  float v[8];
  float s = 0;
  for (int i = 0; i < 8; i++) { v[i] = xr[lane + 64 * i]; s += v[i]; }
  s = wave_sum(s);
  float mu = s * (1.f / 512.f);
  float q = 0;
  for (int i = 0; i < 8; i++) { float d = v[i] - mu; q += d * d; }
  q = wave_sum(q);
  float rstd = rsqrtf(q * (1.f / 512.f) + 1e-5f);
  for (int i = 0; i < 8; i++) {
    int c = lane + 64 * i;
    dst[(size_t)row * E_DIM + c] =
        __float2bfloat16((v[i] - mu) * rstd * lnw[e * E_DIM + c] + lnb[e * E_DIM + c]);
  }
}

// tiled transpose: v[4096][512] -> vT[512][VT_STRIDE] at padded columns pmap[row];
// blocks with blockIdx.x < 8 also zero group blockIdx.x's padded gap for their d-range
__global__ void transpose_v(const short* __restrict__ v, const int* __restrict__ pmap,
                            const int* __restrict__ offs, const int* __restrict__ padoffs,
                            short* __restrict__ vT) {
  __shared__ short tile[64][65];
  int r0 = blockIdx.x * 64, c0 = blockIdx.y * 64;
  int tc = threadIdx.x & 63, tr4 = threadIdx.x >> 6;
  for (int i = 0; i < 64; i += 4)
    tile[tr4 + i][tc] = v[(size_t)(r0 + tr4 + i) * E_DIM + c0 + tc];
  __syncthreads();
  int pcol = pmap[r0 + tc];
  for (int i = 0; i < 64; i += 4)
    vT[(size_t)(c0 + tr4 + i) * VT_STRIDE + pcol] = tile[tc][tr4 + i];
  // fused gap zeroing (masked P=0 must hit finite V)
  int gg = blockIdx.x;
  if (gg < 8) {
    int cnt = offs[gg + 1] - offs[gg];
    int gap = (padoffs[gg + 1] - padoffs[gg]) - cnt;
    int colbase = padoffs[gg] + cnt;
    if (gap > 0) {
      for (int dl = 0; dl < 64; dl += 4) {
        int d = c0 + dl + tr4;
        if (tc < gap) vT[(size_t)d * VT_STRIDE + colbase + tc] = 0;
      }
    }
  }
}

// flash attention, swapped-QK, zero-shuffle PV, defer-max, KVBLK=64,
// triple-buffered LDS with counted vmcnt, setprio around MFMA.
// 1-D grid, XCD-remapped: g = d&7 (one group per XCD), then h, q-block.
__global__ __launch_bounds__(256) void attn_mfma(
    const short* __restrict__ qb, const short* __restrict__ kb,
    const short* __restrict__ vT, const int* __restrict__ offs,
    const int* __restrict__ padoffs, __hip_bfloat16* __restrict__ ob) {
  int d0 = blockIdx.x;
  int g = d0 & 7;
  int rem = d0 >> 3;
  int h = rem >> 5;
  int qblk = rem & 31;
  int sbeg = offs[g], rend = offs[g + 1];
  int q0 = sbeg + qblk * 64;
  if (q0 >= rend) return;
  int G = rend - sbeg;
  int pg = padoffs[g];
  int tid = threadIdx.x, wid = tid >> 6, lane = tid & 63;
  int fr = lane & 15, lg = lane >> 4;
  int qw = q0 + wid * 16;

  __shared__ short Kt[3][64 * 64];   // [key][ch], 128B rows, swz ((key&7)<<4)  (8KB/buf)
  __shared__ short Vt[3][64 * 64];   // [d][key],  128B rows, swz ((d&7)<<4)    (8KB/buf)

  int arow = qw + fr; if (arow > rend - 1) arow = rend - 1;
  const short* qp = qb + (size_t)arow * E_DIM + h * DHEAD;
  short8 qf0 = *reinterpret_cast<const short8*>(qp + lg * 8);
  short8 qf1 = *reinterpret_cast<const short8*>(qp + 32 + lg * 8);

  // staging geometry: 2 chunks x 4KB per buffer; linear dest, pre-swizzled source
  int st_row[2], st_src[2];
  int wb = wid << 9;                          // wave-uniform chunk base (shorts)
  for (int c = 0; c < 2; c++) {
    int off = c * 4096 + tid * 16;
    int row = off >> 7, inner = off & 127;
    st_row[c] = row;
    st_src[c] = (inner ^ ((row & 7) << 4)) >> 1;
  }

  auto stage = [&](int buf, int kbase) {
#pragma unroll
    for (int c = 0; c < 2; c++) {
      int gr = sbeg + kbase + st_row[c]; if (gr > NROW_ - 1) gr = NROW_ - 1;
      gld16(kb + (size_t)gr * E_DIM + h * DHEAD + st_src[c], &Kt[buf][c * 2048 + wb]);
      gld16(vT + (size_t)(h * DHEAD + st_row[c]) * VT_STRIDE + pg + kbase + st_src[c],
            &Vt[buf][c * 2048 + wb]);
    }
  };

  floatx4 acc[4] = {};
  float m_r = -1e30f, l_r = 0.f;
  int nt = (G + 63) >> 6;

  stage(0, 0);
  if (nt > 1) stage(1, 64);
  if (nt > 1) asm volatile("s_waitcnt vmcnt(4)" ::: "memory");
  else        asm volatile("s_waitcnt vmcnt(0)" ::: "memory");
  __builtin_amdgcn_s_barrier();
  __builtin_amdgcn_sched_barrier(0);

  int bcur = 0;
  for (int t = 0; t < nt; ++t) {
    int kbase = t * 64;
    int b2 = bcur + 2; if (b2 >= 3) b2 -= 3;
    if (t + 2 < nt) stage(b2, kbase + 128);
    const char* Kb = (const char*)&Kt[bcur][0];
    const char* Vb = (const char*)&Vt[bcur][0];

    // QK^T: 4 key-subtiles of 16 rows
    floatx4 s[4];
    __builtin_amdgcn_s_setprio(1);
#pragma unroll
    for (int c = 0; c < 4; c++) {
      int rc = c * 16 + fr;
      int sx = (rc & 7) << 4;
      short8 kf0 = *reinterpret_cast<const short8*>(Kb + rc * 128 + ((lg * 16) ^ sx));
      short8 kf1 = *reinterpret_cast<const short8*>(Kb + rc * 128 + ((64 + lg * 16) ^ sx));
      floatx4 z = {};
      z = __builtin_amdgcn_mfma_f32_16x16x32_bf16(kf0, qf0, z, 0, 0, 0);
      z = __builtin_amdgcn_mfma_f32_16x16x32_bf16(kf1, qf1, z, 0, 0, 0);
      s[c] = z;
    }
    __builtin_amdgcn_s_setprio(0);

    // lane (q=fr, lg) holds keys kbase + c*16 + 4lg + j
    float sv[16];
    float mloc = -1e30f;
#pragma unroll
    for (int c = 0; c < 4; c++)
#pragma unroll
      for (int j = 0; j < 4; j++) {
        int k0 = kbase + c * 16 + lg * 4 + j;
        float v = (k0 < G) ? s[c][j] * 0.125f : -1e30f;
        sv[c * 4 + j] = v;
        mloc = fmaxf(mloc, v);
      }
    mloc = fmaxf(mloc, __shfl_xor(mloc, 16));
    mloc = fmaxf(mloc, __shfl_xor(mloc, 32));
    // defer-max: rescale only when the running max grows by > 8
    if (__any(mloc > m_r + 8.f)) {
      float mn = fmaxf(m_r, mloc);
      float corr = __expf(m_r - mn);
      m_r = mn;
      l_r *= corr;
      float cq0 = __shfl(corr, lg * 4 + 0), cq1 = __shfl(corr, lg * 4 + 1);
      float cq2 = __shfl(corr, lg * 4 + 2), cq3 = __shfl(corr, lg * 4 + 3);
#pragma unroll
      for (int db = 0; db < 4; db++) {
        acc[db][0] *= cq0; acc[db][1] *= cq1; acc[db][2] *= cq2; acc[db][3] *= cq3;
      }
    }
    float p[16], sl = 0.f;
#pragma unroll
    for (int i = 0; i < 16; i++) { p[i] = __expf(sv[i] - m_r); sl += p[i]; }
    sl += __shfl_xor(sl, 16);
    sl += __shfl_xor(sl, 32);
    l_r += sl;

    // zero-shuffle PV: per 16-key subtile c, A slots 0-1 = P(keys c*16+4lg+j), rest 0
    union { unsigned u[4]; short8 s8; } pa[4];
#pragma unroll
    for (int c = 0; c < 4; c++) {
      pa[c].u[0] = pack_bf2(p[c * 4 + 0], p[c * 4 + 1]);
      pa[c].u[1] = pack_bf2(p[c * 4 + 2], p[c * 4 + 3]);
      pa[c].u[2] = 0; pa[c].u[3] = 0;
    }
    __builtin_amdgcn_s_setprio(1);
#pragma unroll
    for (int db = 0; db < 4; db++) {
      int dd = db * 16 + fr;
      int sx = (dd & 7) << 4;
#pragma unroll
      for (int c = 0; c < 4; c++) {
        uint2 w = *reinterpret_cast<const uint2*>(Vb + ((dd * 128 + c * 32 + lg * 8) ^ sx));
        union { unsigned u[4]; short8 s8; } bv;
        bv.u[0] = w.x; bv.u[1] = w.y; bv.u[2] = 0; bv.u[3] = 0;
        acc[db] = __builtin_amdgcn_mfma_f32_16x16x32_bf16(pa[c].s8, bv.s8, acc[db], 0, 0, 0);
      }
    }
    __builtin_amdgcn_s_setprio(0);

    if (t + 1 < nt) {
      if (t + 2 < nt) asm volatile("s_waitcnt vmcnt(4)" ::: "memory");
      else            asm volatile("s_waitcnt vmcnt(0)" ::: "memory");
      asm volatile("s_waitcnt lgkmcnt(0)" ::: "memory");
      __builtin_amdgcn_s_barrier();
      __builtin_amdgcn_sched_barrier(0);
    }
    bcur = bcur + 1; if (bcur == 3) bcur = 0;
  }

  float lq0 = __shfl(l_r, lg * 4 + 0), lq1 = __shfl(l_r, lg * 4 + 1);
  float lq2 = __shfl(l_r, lg * 4 + 2), lq3 = __shfl(l_r, lg * 4 + 3);
  float lq[4] = {lq0, lq1, lq2, lq3};
#pragma unroll
  for (int db = 0; db < 4; db++)
#pragma unroll
    for (int j = 0; j < 4; j++) {
      int row = qw + lg * 4 + j;
      if (row < rend)
        ob[(size_t)row * E_DIM + h * DHEAD + db * 16 + fr] = __float2bfloat16(acc[db][j] / lq[j]);
    }
}

// 64xBN-tile MFMA GEMM (BN=128 for modes 0/2/3, 64 for mode 1), triple-buffered LDS,
// depth-2 prefetch, counted vmcnt, 1-D XCD-remapped grid (one group per XCD).
// Each wave computes 32 x BN/2 (acc[2][BN/32]) -> 16 MFMAs/step/wave at BN=128.
// MODE 0: QKV -> q/k/v bf16 split     (K=512,  N=1536)
// MODE 1: out-proj + x residual -> x1 (K=512,  N=512)
// MODE 2: MLP1 + exact GELU -> bf16   (K=512,  N=2048)
// MODE 3: MLP2 split-K x2 -> y1 (=val+bias+resid) / y2 (=val) (K=2048, N=512)
template <int MODE>
__global__ __launch_bounds__(256) void gemm_mfma(
    const short* __restrict__ A, const short* __restrict__ Wb,
    const float* __restrict__ bias, const int* __restrict__ offs,
    const int* __restrict__ perm, const float* __restrict__ resid,
    __hip_bfloat16* __restrict__ bq, __hip_bfloat16* __restrict__ bk,
    __hip_bfloat16* __restrict__ bv, float* __restrict__ outf,
    float* __restrict__ outf2) {
  constexpr int K = (MODE == 3) ? HID_D : E_DIM;
  constexpr int N = (MODE == 0) ? 3 * E_DIM : (MODE == 2) ? HID_D : E_DIM;
  constexpr bool SPLIT = (MODE == 3);
  constexpr int KLEN = SPLIT ? K / 2 : K;
  constexpr int NKSTEP = KLEN / 64;
  constexpr int NXB = 32;
  constexpr int BN = (MODE == 1) ? 64 : 128;
  constexpr int NBCH = BN / 32;          // B staging chunks (4KB each)
  constexpr int NI = BN / 32;            // ni tiles per wave (wave = 32 x BN/2)
  __shared__ short Abuf[3][4096];        // [buf][64 rows][64 k], 128B rows, linear
  __shared__ short Bbuf[3][BN * 64];

  int d = blockIdx.x;
  int g = d & 7;                    // one group per XCD: L2-resident panels
  int rem = d >> 3;
  int ksel = 0;
  if constexpr (SPLIT) { ksel = rem & 1; rem >>= 1; }
  int yb = rem / NXB, xb = rem % NXB;   // xb innermost: same-panel blocks adjacent
  int e = g & 3;
  int rbeg = offs[g], rend = offs[g + 1];
  int row0 = rbeg + xb * 64;
  if (row0 >= rend) return;
  int col0 = yb * BN;
  int kbeg = ksel * KLEN;
  int tid = threadIdx.x;
  int wid = tid >> 6, lane = tid & 63;
  int wm = wid >> 1, wn = wid & 1;
  int fr = lane & 15, lg = lane >> 4;
  const short* wbase = Wb + (size_t)e * N * K;

  // A staging: 2 chunks; B staging: NBCH chunks
  int st_row[2], st_src[2], st_arow[2];
  int bt_row[NBCH], bt_src[NBCH];
  int wavebase = wid << 9;
  for (int c = 0; c < 2; c++) {
    int off = c * 4096 + tid * 16;
    int trow = off >> 7, inner = off & 127;
    st_row[c] = trow;
    st_src[c] = (inner ^ ((trow & 7) << 4)) >> 1;
    int ga = row0 + trow;
    st_arow[c] = ga < rend ? ga : rend - 1;
  }
  for (int c = 0; c < NBCH; c++) {
    int off = c * 4096 + tid * 16;
    int trow = off >> 7, inner = off & 127;
    bt_row[c] = trow;
    bt_src[c] = (inner ^ ((trow & 7) << 4)) >> 1;
  }

  auto stage = [&](int buf, int kb) {
#pragma unroll
    for (int c = 0; c < 2; c++)
      gld16(A + (size_t)st_arow[c] * K + kb + st_src[c], &Abuf[buf][c * 2048 + wavebase]);
#pragma unroll
    for (int c = 0; c < NBCH; c++)
      gld16(wbase + (size_t)(col0 + bt_row[c]) * K + kb + bt_src[c],
            &Bbuf[buf][c * 2048 + wavebase]);
  };

  auto wait_lps = [&]() {
    if constexpr (MODE == 1) asm volatile("s_waitcnt vmcnt(4)" ::: "memory");
    else                     asm volatile("s_waitcnt vmcnt(6)" ::: "memory");
  };

  floatx4 acc[2][NI] = {};
  stage(0, kbeg);
  stage(1, kbeg + 64);
  wait_lps();                          // tile0 landed; tile1 in flight
  __builtin_amdgcn_s_barrier();
  __builtin_amdgcn_sched_barrier(0);

  int bcur = 0;
  for (int t = 0; t < NKSTEP; ++t) {
    int b2 = bcur + 2; if (b2 >= 3) b2 -= 3;
    if (t + 2 < NKSTEP) stage(b2, kbeg + (t + 2) * 64);
    const char* Ab = (const char*)&Abuf[bcur][0];
    const char* Bb = (const char*)&Bbuf[bcur][0];
    short8 af[2][2], bf8[NI][2];
#pragma unroll
    for (int mi = 0; mi < 2; mi++)
#pragma unroll
      for (int ks = 0; ks < 2; ks++) {
        int row = wm * 32 + mi * 16 + fr;
        int cb = ks * 64 + lg * 16;
        af[mi][ks] = *reinterpret_cast<const short8*>(Ab + row * 128 + (cb ^ ((row & 7) << 4)));
      }
#pragma unroll
    for (int ni = 0; ni < NI; ni++)
#pragma unroll
      for (int ks = 0; ks < 2; ks++) {
        int row = wn * (BN / 2) + ni * 16 + fr;
        int cb = ks * 64 + lg * 16;
        bf8[ni][ks] = *reinterpret_cast<const short8*>(Bb + row * 128 + (cb ^ ((row & 7) << 4)));
      }
#pragma unroll
    for (int mi = 0; mi < 2; mi++)
#pragma unroll
      for (int ni = 0; ni < NI; ni++) {
        acc[mi][ni] = __builtin_amdgcn_mfma_f32_16x16x32_bf16(af[mi][0], bf8[ni][0], acc[mi][ni], 0, 0, 0);
        acc[mi][ni] = __builtin_amdgcn_mfma_f32_16x16x32_bf16(af[mi][1], bf8[ni][1], acc[mi][ni], 0, 0, 0);
      }
    if (t + 1 < NKSTEP) {
      if (t + 2 < NKSTEP) wait_lps();   // next tile landed, one still in flight
      else                asm volatile("s_waitcnt vmcnt(0)" ::: "memory");
      asm volatile("s_waitcnt lgkmcnt(0)" ::: "memory");
      __builtin_amdgcn_s_barrier();
      __builtin_amdgcn_sched_barrier(0);
    }
    bcur = (bcur + 1 == 3) ? 0 : bcur + 1;
  }

  for (int mi = 0; mi < 2; mi++)
    for (int ni = 0; ni < NI; ni++)
      for (int j = 0; j < 4; j++) {
        int row = row0 + wm * 32 + mi * 16 + lg * 4 + j;
        if (row >= rend) continue;
        int col = col0 + wn * (BN / 2) + ni * 16 + fr;
        float val = acc[mi][ni][j];
        if constexpr (MODE != 3) val += bias[e * N + col];
        if constexpr (MODE == 0) {
          if (col < E_DIM) bq[(size_t)row * E_DIM + col] = __float2bfloat16(val);
          else if (col < 2 * E_DIM) bk[(size_t)row * E_DIM + col - E_DIM] = __float2bfloat16(val);
          else bv[(size_t)row * E_DIM + col - 2 * E_DIM] = __float2bfloat16(val);
        } else if constexpr (MODE == 1) {
          int t = perm[row];
          outf[(size_t)row * E_DIM + col] = val + resid[(size_t)t * E_DIM + col];
        } else if constexpr (MODE == 2) {
          float gl = 0.5f * val * (1.f + erff(val * 0.70710678118654752f));
          bq[(size_t)row * HID_D + col] = __float2bfloat16(gl);
        } else {
          if (ksel == 0) {
            val += bias[e * N + col] + resid[(size_t)row * E_DIM + col];
            outf[(size_t)row * E_DIM + col] = val;
          } else {
            outf2[(size_t)row * E_DIM + col] = val;
          }
        }
      }
}

// out[t] = sum_kk p_kk * (y1[row_kk] + y2[row_kk])   (fixed order: deterministic)
__global__ void combine_kernel(const float* __restrict__ y1, const float* __restrict__ y2,
                               const int* __restrict__ invrow,
                               const float* __restrict__ token_p, float* __restrict__ out) {
  int t = blockIdx.x;
  int r0 = invrow[t], r1 = invrow[T_TOK + t];
  float p0 = token_p[t], p1 = token_p[T_TOK + t];
  const float4* a0 = (const float4*)(y1 + (size_t)r0 * E_DIM);
  const float4* b0 = (const float4*)(y2 + (size_t)r0 * E_DIM);
  const float4* a1 = (const float4*)(y1 + (size_t)r1 * E_DIM);
  const float4* b1 = (const float4*)(y2 + (size_t)r1 * E_DIM);
  float4* o = (float4*)(out + (size_t)t * E_DIM);
  int i = threadIdx.x;
  float4 va0 = a0[i], vb0 = b0[i], va1 = a1[i], vb1 = b1[i];
  float4 r;
  r.x = p0 * (va0.x + vb0.x) + p1 * (va1.x + vb1.x);
  r.y = p0 * (va0.y + vb0.y) + p1 * (va1.y + vb1.y);
  r.z = p0 * (va0.z + vb0.z) + p1 * (va1.z + vb1.z);
  r.w = p0 * (va0.w + vb0.w) + p1 * (va1.w + vb1.w);
  o[i] = r;
}

extern "C" void kernel_launch(void* const* d_in, const int* in_sizes, int n_in,
                              void* d_out, int out_size, void* d_ws, size_t ws_size,
                              hipStream_t stream) {
  const float* x      = (const float*)d_in[0];
  const float* gate_w = (const float*)d_in[1];
  const float* gate_b = (const float*)d_in[2];
  const float* ln1_w  = (const float*)d_in[3];
  const float* ln1_b  = (const float*)d_in[4];
  const float* ipw    = (const float*)d_in[5];
  const float* ipb    = (const float*)d_in[6];
  const float* opw    = (const float*)d_in[7];
  const float* opb    = (const float*)d_in[8];
  const float* ln2_w  = (const float*)d_in[9];
  const float* ln2_b  = (const float*)d_in[10];
  const float* w1     = (const float*)d_in[11];
  const float* b1     = (const float*)d_in[12];
  const float* w2     = (const float*)d_in[13];
  const float* b2     = (const float*)d_in[14];
  float* out = (float*)d_out;

  const int SZ_IP = NEXP * 3 * E_DIM * E_DIM;
  const int SZ_OP = NEXP * E_DIM * E_DIM;
  const int SZ_W1 = NEXP * HID_D * E_DIM;
  const int SZ_W2 = NEXP * E_DIM * HID_D;
  const int NROW = NROW_;

  char* ws = (char*)d_ws;
  size_t off = 0;
  auto carve = [&](size_t bytes) -> void* {
    void* p = ws + off;
    off += (bytes + 255) & ~(size_t)255;
    return p;
  };
  __hip_bfloat16* ipw_bf = (__hip_bfloat16*)carve((size_t)SZ_IP * 2);
  __hip_bfloat16* opw_bf = (__hip_bfloat16*)carve((size_t)SZ_OP * 2);
  __hip_bfloat16* w1_bf  = (__hip_bfloat16*)carve((size_t)SZ_W1 * 2);
  __hip_bfloat16* w2_bf  = (__hip_bfloat16*)carve((size_t)SZ_W2 * 2);
  __hip_bfloat16* h_bf   = (__hip_bfloat16*)carve((size_t)NROW * E_DIM * 2);
  __hip_bfloat16* q_bf   = (__hip_bfloat16*)carve((size_t)NROW * E_DIM * 2);
  __hip_bfloat16* k_bf   = (__hip_bfloat16*)carve((size_t)NROW * E_DIM * 2);
  __hip_bfloat16* v_bf   = (__hip_bfloat16*)carve((size_t)NROW * E_DIM * 2);
  __hip_bfloat16* o_bf   = (__hip_bfloat16*)carve((size_t)NROW * E_DIM * 2);
  __hip_bfloat16* h2_bf  = (__hip_bfloat16*)carve((size_t)NROW * E_DIM * 2);
  __hip_bfloat16* mid_bf = (__hip_bfloat16*)carve((size_t)NROW * HID_D * 2);
  short* vT     = (short*)carve((size_t)E_DIM * VT_STRIDE * 2);
  float* x1     = (float*)carve((size_t)NROW * E_DIM * 4);
  int* token_e  = (int*)carve((size_t)NROW * 4);
  float* token_p= (float*)carve((size_t)NROW * 4);
  int* perm     = (int*)carve((size_t)NROW * 4);
  int* rowg     = (int*)carve((size_t)NROW * 4);
  int* pmap     = (int*)carve((size_t)NROW * 4);
  int* invrow   = (int*)carve((size_t)NROW * 4);
  int* offs     = (int*)carve(9 * 4);
  int* padoffs  = (int*)carve(9 * 4);
  // y1[4096][512] fp32 (8 MB) aliases h_bf+q_bf; y2 aliases k_bf+v_bf (all dead by MODE 3)
  float* ybuf  = (float*)h_bf;
  float* ybuf2 = (float*)k_bf;

  cvt_weights<<<SZ_W1 / 4 / 256, 256, 0, stream>>>(ipw, opw, w1, w2, ipw_bf, opw_bf,
                                                   w1_bf, w2_bf, SZ_IP, SZ_OP, SZ_W1, SZ_W2);
  gate_kernel<<<T_TOK / 4, 256, 0, stream>>>(x, gate_w, gate_b, token_e, token_p);
  route_kernel<<<8, 256, 0, stream>>>(token_e, perm, rowg, pmap, invrow, offs, padoffs);
  ln_kernel<<<NROW / 4, 256, 0, stream>>>(x, perm, rowg, ln1_w, ln1_b, h_bf);
  gemm_mfma<0><<<8 * 12 * 32, 256, 0, stream>>>((const short*)h_bf, (const short*)ipw_bf,
      ipb, offs, perm, nullptr, q_bf, k_bf, v_bf, nullptr, nullptr);
  transpose_v<<<dim3(NROW / 64, E_DIM / 64), 256, 0, stream>>>((const short*)v_bf, pmap,
      offs, padoffs, vT);
  attn_mfma<<<8 * 8 * 32, 256, 0, stream>>>((const short*)q_bf, (const short*)k_bf,
      vT, offs, padoffs, o_bf);
  gemm_mfma<1><<<8 * 8 * 32, 256, 0, stream>>>((const short*)o_bf, (const short*)opw_bf,
      opb, offs, perm, x, nullptr, nullptr, nullptr, x1, nullptr);
  ln_kernel<<<NROW / 4, 256, 0, stream>>>(x1, nullptr, rowg, ln2_w, ln2_b, h2_bf);
  gemm_mfma<2><<<8 * 16 * 32, 256, 0, stream>>>((const short*)h2_bf, (const short*)w1_bf,
      b1, offs, perm, nullptr, mid_bf, nullptr, nullptr, nullptr, nullptr);
  gemm_mfma<3><<<8 * 2 * 4 * 32, 256, 0, stream>>>((const short*)mid_bf, (const short*)w2_bf,
      b2, offs, perm, x1, nullptr, nullptr, nullptr, ybuf, ybuf2);
  combine_kernel<<<T_TOK, 128, 0, stream>>>(ybuf, ybuf2, invrow, token_p, out);
  (void)in_sizes; (void)n_in; (void)ws_size;
}

// Round 13
// 174.640 us; speedup vs baseline: 1.1103x; 1.1103x over previous
//
#include <hip/hip_runtime.h>
#include <hip/hip_bf16.h>

#define T_TOK 2048
#define E_DIM 512
#define NHEAD 8
#define DHEAD 64
#define HID_D 2048
#define NEXP 4
#define NROW_ (2 * T_TOK)
#define VT_STRIDE 4608

typedef short short8 __attribute__((ext_vector_type(8)));
typedef float floatx4 __attribute__((ext_vector_type(4)));

__device__ __forceinline__ void gld16(const void* g, void* l) {
  __builtin_amdgcn_global_load_lds((const __attribute__((address_space(1))) void*)g,
                                   (__attribute__((address_space(3))) void*)l, 16, 0, 0);
}

__device__ inline float wave_sum(float v) {
  for (int off = 32; off > 0; off >>= 1) v += __shfl_xor(v, off);
  return v;
}

__device__ __forceinline__ unsigned pack_bf2(float a, float b) {
  __hip_bfloat16 ha = __float2bfloat16(a), hb = __float2bfloat16(b);
  unsigned ua = *(unsigned short*)&ha, ub = *(unsigned short*)&hb;
  return ua | (ub << 16);
}

__device__ __forceinline__ void cvt4(const float* __restrict__ s, __hip_bfloat16* __restrict__ d,
                                     int i4, int n) {
  if (i4 < n) {
    float4 v = *reinterpret_cast<const float4*>(s + i4);
    __hip_bfloat16 tmp[4] = {__float2bfloat16(v.x), __float2bfloat16(v.y),
                             __float2bfloat16(v.z), __float2bfloat16(v.w)};
    *reinterpret_cast<ushort4*>(d + i4) = *reinterpret_cast<const ushort4*>(tmp);
  }
}

__global__ void cvt_weights(const float* __restrict__ s0, const float* __restrict__ s1,
                            const float* __restrict__ s2, const float* __restrict__ s3,
                            __hip_bfloat16* d0, __hip_bfloat16* d1,
                            __hip_bfloat16* d2, __hip_bfloat16* d3,
                            int n0, int n1, int n2, int n3) {
  int i4 = (blockIdx.x * 256 + threadIdx.x) * 4;
  cvt4(s0, d0, i4, n0);
  cvt4(s1, d1, i4, n1);
  cvt4(s2, d2, i4, n2);
  cvt4(s3, d3, i4, n3);
}

// one wave per token: 4 gate dots, top-2, softmax probs
__global__ void gate_kernel(const float* __restrict__ x, const float* __restrict__ gw,
                            const float* __restrict__ gb, int* token_e, float* token_p) {
  int wid = threadIdx.x >> 6, lane = threadIdx.x & 63;
  int t = blockIdx.x * 4 + wid;
  float a0 = 0, a1 = 0, a2 = 0, a3 = 0;
  for (int i = 0; i < 8; i++) {
    int c = lane + 64 * i;
    float xv = x[(size_t)t * E_DIM + c];
    a0 += xv * gw[0 * E_DIM + c];
    a1 += xv * gw[1 * E_DIM + c];
    a2 += xv * gw[2 * E_DIM + c];
    a3 += xv * gw[3 * E_DIM + c];
  }
  a0 = wave_sum(a0); a1 = wave_sum(a1); a2 = wave_sum(a2); a3 = wave_sum(a3);
  if (lane == 0) {
    float lg[4] = {a0 + gb[0], a1 + gb[1], a2 + gb[2], a3 + gb[3]};
    int i0 = 0;
    for (int e = 1; e < 4; e++) if (lg[e] > lg[i0]) i0 = e;   // strict > : lowest idx on tie
    int i1 = -1;
    for (int e = 0; e < 4; e++) {
      if (e == i0) continue;
      if (i1 < 0 || lg[e] > lg[i1]) i1 = e;
    }
    float e1 = __expf(lg[i1] - lg[i0]);
    float inv = 1.f / (1.f + e1);
    token_e[t] = i0; token_e[T_TOK + t] = i1;
    token_p[t] = inv; token_p[T_TOK + t] = e1 * inv;
  }
}

// fused count + prefix + stable compaction (8 blocks; each recomputes all counts)
__global__ void route_kernel(const int* __restrict__ token_e, int* perm, int* rowg,
                             int* pmap, int* invrow, int* offs_out, int* padoffs_out) {
  int g = blockIdx.x, kk = g >> 2, e = g & 3;
  int tid = threadIdx.x, wid = tid >> 6, lane = tid & 63;
  __shared__ int cnt_s[8][4];
  for (int gg = 0; gg < 8; gg++) {
    int kk2 = gg >> 2, e2 = gg & 3;
    int c = 0;
    for (int t = tid; t < T_TOK; t += 256) c += (token_e[kk2 * T_TOK + t] == e2);
    for (int off = 32; off; off >>= 1) c += __shfl_xor(c, off);
    if (lane == 0) cnt_s[gg][wid] = c;
  }
  __syncthreads();
  int offs[9], padoffs[9];
  offs[0] = 0; padoffs[0] = 0;
  for (int gg = 0; gg < 8; gg++) {
    int c = cnt_s[gg][0] + cnt_s[gg][1] + cnt_s[gg][2] + cnt_s[gg][3];
    offs[gg + 1] = offs[gg] + c;
    padoffs[gg + 1] = padoffs[gg] + ((c + 63) & ~63);
  }
  if (g == 0 && tid < 9) { offs_out[tid] = offs[tid]; padoffs_out[tid] = padoffs[tid]; }
  int og = offs[g], pg = padoffs[g];
  __shared__ int wcnt[4];
  __shared__ int base;
  if (tid == 0) base = 0;
  __syncthreads();
  for (int t0 = 0; t0 < T_TOK; t0 += 256) {
    int t = t0 + tid;
    bool pred = token_e[kk * T_TOK + t] == e;
    unsigned long long mask = __ballot(pred);
    int rank = __popcll(mask & ((1ull << lane) - 1ull));
    if (lane == 0) wcnt[wid] = __popcll(mask);
    __syncthreads();
    int woff = 0;
    for (int i = 0; i < wid; i++) woff += wcnt[i];
    if (pred) {
      int row = og + base + woff + rank;
      perm[row] = t;
      rowg[row] = g;
      pmap[row] = pg + (row - og);
      invrow[kk * T_TOK + t] = row;
    }
    __syncthreads();
    if (tid == 0) base += wcnt[0] + wcnt[1] + wcnt[2] + wcnt[3];
    __syncthreads();
  }
}

// one wave per row: LayerNorm -> bf16.  perm==nullptr: src row-indexed.
__global__ void ln_kernel(const float* __restrict__ src, const int* __restrict__ perm,
                          const int* __restrict__ rowg, const float* __restrict__ lnw,
                          const float* __restrict__ lnb, __hip_bfloat16* __restrict__ dst) {
  int wid = threadIdx.x >> 6, lane = threadIdx.x & 63;
  int row = blockIdx.x * 4 + wid;
  int e = rowg[row] & 3;
  const float* xr = src + (size_t)(perm ? perm[row] : row) * E_DIM;
  float v[8];
  float s = 0;
  for (int i = 0; i < 8; i++) { v[i] = xr[lane + 64 * i]; s += v[i]; }
  s = wave_sum(s);
  float mu = s * (1.f / 512.f);
  float q = 0;
  for (int i = 0; i < 8; i++) { float d = v[i] - mu; q += d * d; }
  q = wave_sum(q);
  float rstd = rsqrtf(q * (1.f / 512.f) + 1e-5f);
  for (int i = 0; i < 8; i++) {
    int c = lane + 64 * i;
    dst[(size_t)row * E_DIM + c] =
        __float2bfloat16((v[i] - mu) * rstd * lnw[e * E_DIM + c] + lnb[e * E_DIM + c]);
  }
}

// tiled transpose: v[4096][512] -> vT[512][VT_STRIDE] at padded columns pmap[row];
// blocks with blockIdx.x < 8 also zero group blockIdx.x's padded gap for their d-range
__global__ void transpose_v(const short* __restrict__ v, const int* __restrict__ pmap,
                            const int* __restrict__ offs, const int* __restrict__ padoffs,
                            short* __restrict__ vT) {
  __shared__ short tile[64][65];
  int r0 = blockIdx.x * 64, c0 = blockIdx.y * 64;
  int tc = threadIdx.x & 63, tr4 = threadIdx.x >> 6;
  for (int i = 0; i < 64; i += 4)
    tile[tr4 + i][tc] = v[(size_t)(r0 + tr4 + i) * E_DIM + c0 + tc];
  __syncthreads();
  int pcol = pmap[r0 + tc];
  for (int i = 0; i < 64; i += 4)
    vT[(size_t)(c0 + tr4 + i) * VT_STRIDE + pcol] = tile[tc][tr4 + i];
  // fused gap zeroing (masked P=0 must hit finite V)
  int gg = blockIdx.x;
  if (gg < 8) {
    int cnt = offs[gg + 1] - offs[gg];
    int gap = (padoffs[gg + 1] - padoffs[gg]) - cnt;
    int colbase = padoffs[gg] + cnt;
    if (gap > 0) {
      for (int dl = 0; dl < 64; dl += 4) {
        int d = c0 + dl + tr4;
        if (tc < gap) vT[(size_t)d * VT_STRIDE + colbase + tc] = 0;
      }
    }
  }
}

// flash attention, swapped-QK, zero-shuffle PV, defer-max, KVBLK=64,
// triple-buffered LDS with counted vmcnt, setprio around MFMA.
// 1-D grid, XCD-remapped: g = d&7 (one group per XCD), then h, q-block.
__global__ __launch_bounds__(256) void attn_mfma(
    const short* __restrict__ qb, const short* __restrict__ kb,
    const short* __restrict__ vT, const int* __restrict__ offs,
    const int* __restrict__ padoffs, __hip_bfloat16* __restrict__ ob) {
  int d0 = blockIdx.x;
  int g = d0 & 7;
  int rem = d0 >> 3;
  int h = rem >> 5;
  int qblk = rem & 31;
  int sbeg = offs[g], rend = offs[g + 1];
  int q0 = sbeg + qblk * 64;
  if (q0 >= rend) return;
  int G = rend - sbeg;
  int pg = padoffs[g];
  int tid = threadIdx.x, wid = tid >> 6, lane = tid & 63;
  int fr = lane & 15, lg = lane >> 4;
  int qw = q0 + wid * 16;

  __shared__ short Kt[3][64 * 64];   // [key][ch], 128B rows, swz ((key&7)<<4)  (8KB/buf)
  __shared__ short Vt[3][64 * 64];   // [d][key],  128B rows, swz ((d&7)<<4)    (8KB/buf)

  int arow = qw + fr; if (arow > rend - 1) arow = rend - 1;
  const short* qp = qb + (size_t)arow * E_DIM + h * DHEAD;
  short8 qf0 = *reinterpret_cast<const short8*>(qp + lg * 8);
  short8 qf1 = *reinterpret_cast<const short8*>(qp + 32 + lg * 8);

  // staging geometry: 2 chunks x 4KB per buffer; linear dest, pre-swizzled source
  int st_row[2], st_src[2];
  int wb = wid << 9;                          // wave-uniform chunk base (shorts)
  for (int c = 0; c < 2; c++) {
    int off = c * 4096 + tid * 16;
    int row = off >> 7, inner = off & 127;
    st_row[c] = row;
    st_src[c] = (inner ^ ((row & 7) << 4)) >> 1;
  }

  auto stage = [&](int buf, int kbase) {
#pragma unroll
    for (int c = 0; c < 2; c++) {
      int gr = sbeg + kbase + st_row[c]; if (gr > NROW_ - 1) gr = NROW_ - 1;
      gld16(kb + (size_t)gr * E_DIM + h * DHEAD + st_src[c], &Kt[buf][c * 2048 + wb]);
      gld16(vT + (size_t)(h * DHEAD + st_row[c]) * VT_STRIDE + pg + kbase + st_src[c],
            &Vt[buf][c * 2048 + wb]);
    }
  };

  floatx4 acc[4] = {};
  float m_r = -1e30f, l_r = 0.f;
  int nt = (G + 63) >> 6;

  stage(0, 0);
  if (nt > 1) stage(1, 64);
  if (nt > 1) asm volatile("s_waitcnt vmcnt(4)" ::: "memory");
  else        asm volatile("s_waitcnt vmcnt(0)" ::: "memory");
  __builtin_amdgcn_s_barrier();
  __builtin_amdgcn_sched_barrier(0);

  int bcur = 0;
  for (int t = 0; t < nt; ++t) {
    int kbase = t * 64;
    int b2 = bcur + 2; if (b2 >= 3) b2 -= 3;
    if (t + 2 < nt) stage(b2, kbase + 128);
    const char* Kb = (const char*)&Kt[bcur][0];
    const char* Vb = (const char*)&Vt[bcur][0];

    // QK^T: 4 key-subtiles of 16 rows
    floatx4 s[4];
    __builtin_amdgcn_s_setprio(1);
#pragma unroll
    for (int c = 0; c < 4; c++) {
      int rc = c * 16 + fr;
      int sx = (rc & 7) << 4;
      short8 kf0 = *reinterpret_cast<const short8*>(Kb + rc * 128 + ((lg * 16) ^ sx));
      short8 kf1 = *reinterpret_cast<const short8*>(Kb + rc * 128 + ((64 + lg * 16) ^ sx));
      floatx4 z = {};
      z = __builtin_amdgcn_mfma_f32_16x16x32_bf16(kf0, qf0, z, 0, 0, 0);
      z = __builtin_amdgcn_mfma_f32_16x16x32_bf16(kf1, qf1, z, 0, 0, 0);
      s[c] = z;
    }
    __builtin_amdgcn_s_setprio(0);

    // lane (q=fr, lg) holds keys kbase + c*16 + 4lg + j
    float sv[16];
    float mloc = -1e30f;
#pragma unroll
    for (int c = 0; c < 4; c++)
#pragma unroll
      for (int j = 0; j < 4; j++) {
        int k0 = kbase + c * 16 + lg * 4 + j;
        float v = (k0 < G) ? s[c][j] * 0.125f : -1e30f;
        sv[c * 4 + j] = v;
        mloc = fmaxf(mloc, v);
      }
    mloc = fmaxf(mloc, __shfl_xor(mloc, 16));
    mloc = fmaxf(mloc, __shfl_xor(mloc, 32));
    // defer-max: rescale only when the running max grows by > 8
    if (__any(mloc > m_r + 8.f)) {
      float mn = fmaxf(m_r, mloc);
      float corr = __expf(m_r - mn);
      m_r = mn;
      l_r *= corr;
      float cq0 = __shfl(corr, lg * 4 + 0), cq1 = __shfl(corr, lg * 4 + 1);
      float cq2 = __shfl(corr, lg * 4 + 2), cq3 = __shfl(corr, lg * 4 + 3);
#pragma unroll
      for (int db = 0; db < 4; db++) {
        acc[db][0] *= cq0; acc[db][1] *= cq1; acc[db][2] *= cq2; acc[db][3] *= cq3;
      }
    }
    float p[16], sl = 0.f;
#pragma unroll
    for (int i = 0; i < 16; i++) { p[i] = __expf(sv[i] - m_r); sl += p[i]; }
    sl += __shfl_xor(sl, 16);
    sl += __shfl_xor(sl, 32);
    l_r += sl;

    // zero-shuffle PV: per 16-key subtile c, A slots 0-1 = P(keys c*16+4lg+j), rest 0
    union { unsigned u[4]; short8 s8; } pa[4];
#pragma unroll
    for (int c = 0; c < 4; c++) {
      pa[c].u[0] = pack_bf2(p[c * 4 + 0], p[c * 4 + 1]);
      pa[c].u[1] = pack_bf2(p[c * 4 + 2], p[c * 4 + 3]);
      pa[c].u[2] = 0; pa[c].u[3] = 0;
    }
    __builtin_amdgcn_s_setprio(1);
#pragma unroll
    for (int db = 0; db < 4; db++) {
      int dd = db * 16 + fr;
      int sx = (dd & 7) << 4;
#pragma unroll
      for (int c = 0; c < 4; c++) {
        uint2 w = *reinterpret_cast<const uint2*>(Vb + ((dd * 128 + c * 32 + lg * 8) ^ sx));
        union { unsigned u[4]; short8 s8; } bv;
        bv.u[0] = w.x; bv.u[1] = w.y; bv.u[2] = 0; bv.u[3] = 0;
        acc[db] = __builtin_amdgcn_mfma_f32_16x16x32_bf16(pa[c].s8, bv.s8, acc[db], 0, 0, 0);
      }
    }
    __builtin_amdgcn_s_setprio(0);

    if (t + 1 < nt) {
      if (t + 2 < nt) asm volatile("s_waitcnt vmcnt(4)" ::: "memory");
      else            asm volatile("s_waitcnt vmcnt(0)" ::: "memory");
      asm volatile("s_waitcnt lgkmcnt(0)" ::: "memory");
      __builtin_amdgcn_s_barrier();
      __builtin_amdgcn_sched_barrier(0);
    }
    bcur = bcur + 1; if (bcur == 3) bcur = 0;
  }

  float lq0 = __shfl(l_r, lg * 4 + 0), lq1 = __shfl(l_r, lg * 4 + 1);
  float lq2 = __shfl(l_r, lg * 4 + 2), lq3 = __shfl(l_r, lg * 4 + 3);
  float lq[4] = {lq0, lq1, lq2, lq3};
#pragma unroll
  for (int db = 0; db < 4; db++)
#pragma unroll
    for (int j = 0; j < 4; j++) {
      int row = qw + lg * 4 + j;
      if (row < rend)
        ob[(size_t)row * E_DIM + h * DHEAD + db * 16 + fr] = __float2bfloat16(acc[db][j] / lq[j]);
    }
}

// 64x64-tile MFMA GEMM, triple-buffered LDS, depth-2 prefetch, counted vmcnt,
// 1-D XCD-remapped grid (one group per XCD).
// MODE 0: QKV -> q/k/v bf16 split     (K=512,  N=1536)
// MODE 1: out-proj + x residual -> x1 (K=512,  N=512)
// MODE 2: MLP1 + exact GELU -> bf16   (K=512,  N=2048)
// MODE 3: MLP2 split-K x2 -> y1 (=val+bias+resid) / y2 (=val) (K=2048, N=512)
template <int MODE>
__global__ __launch_bounds__(256) void gemm_mfma(
    const short* __restrict__ A, const short* __restrict__ Wb,
    const float* __restrict__ bias, const int* __restrict__ offs,
    const int* __restrict__ perm, const float* __restrict__ resid,
    __hip_bfloat16* __restrict__ bq, __hip_bfloat16* __restrict__ bk,
    __hip_bfloat16* __restrict__ bv, float* __restrict__ outf,
    float* __restrict__ outf2) {
  constexpr int K = (MODE == 3) ? HID_D : E_DIM;
  constexpr int N = (MODE == 0) ? 3 * E_DIM : (MODE == 2) ? HID_D : E_DIM;
  constexpr bool SPLIT = (MODE == 3);
  constexpr int KLEN = SPLIT ? K / 2 : K;
  constexpr int NKSTEP = KLEN / 64;
  constexpr int NXB = 32;
  __shared__ short Abuf[3][4096];   // [buf][64 rows][64 k], 128B rows, linear
  __shared__ short Bbuf[3][4096];

  int d = blockIdx.x;
  int g = d & 7;                    // one group per XCD: L2-resident panels
  int rem = d >> 3;
  int ksel = 0;
  if constexpr (SPLIT) { ksel = rem & 1; rem >>= 1; }
  int yb = rem / NXB, xb = rem % NXB;   // xb innermost: same-panel blocks adjacent
  int e = g & 3;
  int rbeg = offs[g], rend = offs[g + 1];
  int row0 = rbeg + xb * 64;
  if (row0 >= rend) return;
  int col0 = yb * 64;
  int kbeg = ksel * KLEN;
  int tid = threadIdx.x;
  int wid = tid >> 6, lane = tid & 63;
  int wm = wid >> 1, wn = wid & 1;
  int fr = lane & 15, lg = lane >> 4;
  const short* wbase = Wb + (size_t)e * N * K;

  int st_row[2], st_src[2], st_arow[2];
  int wavebase = wid << 9;
  for (int c = 0; c < 2; c++) {
    int off = c * 4096 + tid * 16;
    int trow = off >> 7;
    int inner = off & 127;
    st_row[c] = trow;
    st_src[c] = (inner ^ ((trow & 7) << 4)) >> 1;
    int ga = row0 + trow;
    st_arow[c] = ga < rend ? ga : rend - 1;
  }

  auto stage = [&](int buf, int kb) {
#pragma unroll
    for (int c = 0; c < 2; c++) {
      gld16(A + (size_t)st_arow[c] * K + kb + st_src[c], &Abuf[buf][c * 2048 + wavebase]);
      gld16(wbase + (size_t)(col0 + st_row[c]) * K + kb + st_src[c],
            &Bbuf[buf][c * 2048 + wavebase]);
    }
  };

  floatx4 acc[2][2] = {};
  stage(0, kbeg);
  stage(1, kbeg + 64);
  asm volatile("s_waitcnt vmcnt(4)" ::: "memory");   // tile0 landed; tile1 in flight
  __builtin_amdgcn_s_barrier();
  __builtin_amdgcn_sched_barrier(0);

  int bcur = 0;
  for (int t = 0; t < NKSTEP; ++t) {
    int b2 = bcur + 2; if (b2 >= 3) b2 -= 3;
    if (t + 2 < NKSTEP) stage(b2, kbeg + (t + 2) * 64);
    const char* Ab = (const char*)&Abuf[bcur][0];
    const char* Bb = (const char*)&Bbuf[bcur][0];
    short8 af[2][2], bf8[2][2];
#pragma unroll
    for (int mi = 0; mi < 2; mi++)
#pragma unroll
      for (int ks = 0; ks < 2; ks++) {
        int row = wm * 32 + mi * 16 + fr;
        int cb = ks * 64 + lg * 16;
        af[mi][ks] = *reinterpret_cast<const short8*>(Ab + row * 128 + (cb ^ ((row & 7) << 4)));
      }
#pragma unroll
    for (int ni = 0; ni < 2; ni++)
#pragma unroll
      for (int ks = 0; ks < 2; ks++) {
        int row = wn * 32 + ni * 16 + fr;
        int cb = ks * 64 + lg * 16;
        bf8[ni][ks] = *reinterpret_cast<const short8*>(Bb + row * 128 + (cb ^ ((row & 7) << 4)));
      }
#pragma unroll
    for (int mi = 0; mi < 2; mi++)
#pragma unroll
      for (int ni = 0; ni < 2; ni++) {
        acc[mi][ni] = __builtin_amdgcn_mfma_f32_16x16x32_bf16(af[mi][0], bf8[ni][0], acc[mi][ni], 0, 0, 0);
        acc[mi][ni] = __builtin_amdgcn_mfma_f32_16x16x32_bf16(af[mi][1], bf8[ni][1], acc[mi][ni], 0, 0, 0);
      }
    if (t + 1 < NKSTEP) {
      if (t + 2 < NKSTEP) asm volatile("s_waitcnt vmcnt(4)" ::: "memory");  // next tile landed
      else                asm volatile("s_waitcnt vmcnt(0)" ::: "memory");
      asm volatile("s_waitcnt lgkmcnt(0)" ::: "memory");
      __builtin_amdgcn_s_barrier();
      __builtin_amdgcn_sched_barrier(0);
    }
    bcur = (bcur + 1 == 3) ? 0 : bcur + 1;
  }

  for (int mi = 0; mi < 2; mi++)
    for (int ni = 0; ni < 2; ni++)
      for (int j = 0; j < 4; j++) {
        int row = row0 + wm * 32 + mi * 16 + lg * 4 + j;
        if (row >= rend) continue;
        int col = col0 + wn * 32 + ni * 16 + fr;
        float val = acc[mi][ni][j];
        if constexpr (MODE != 3) val += bias[e * N + col];
        if constexpr (MODE == 0) {
          if (col < E_DIM) bq[(size_t)row * E_DIM + col] = __float2bfloat16(val);
          else if (col < 2 * E_DIM) bk[(size_t)row * E_DIM + col - E_DIM] = __float2bfloat16(val);
          else bv[(size_t)row * E_DIM + col - 2 * E_DIM] = __float2bfloat16(val);
        } else if constexpr (MODE == 1) {
          int t = perm[row];
          outf[(size_t)row * E_DIM + col] = val + resid[(size_t)t * E_DIM + col];
        } else if constexpr (MODE == 2) {
          float gl = 0.5f * val * (1.f + erff(val * 0.70710678118654752f));
          bq[(size_t)row * HID_D + col] = __float2bfloat16(gl);
        } else {
          if (ksel == 0) {
            val += bias[e * N + col] + resid[(size_t)row * E_DIM + col];
            outf[(size_t)row * E_DIM + col] = val;
          } else {
            outf2[(size_t)row * E_DIM + col] = val;
          }
        }
      }
}

// out[t] = sum_kk p_kk * (y1[row_kk] + y2[row_kk])   (fixed order: deterministic)
__global__ void combine_kernel(const float* __restrict__ y1, const float* __restrict__ y2,
                               const int* __restrict__ invrow,
                               const float* __restrict__ token_p, float* __restrict__ out) {
  int t = blockIdx.x;
  int r0 = invrow[t], r1 = invrow[T_TOK + t];
  float p0 = token_p[t], p1 = token_p[T_TOK + t];
  const float4* a0 = (const float4*)(y1 + (size_t)r0 * E_DIM);
  const float4* b0 = (const float4*)(y2 + (size_t)r0 * E_DIM);
  const float4* a1 = (const float4*)(y1 + (size_t)r1 * E_DIM);
  const float4* b1 = (const float4*)(y2 + (size_t)r1 * E_DIM);
  float4* o = (float4*)(out + (size_t)t * E_DIM);
  int i = threadIdx.x;
  float4 va0 = a0[i], vb0 = b0[i], va1 = a1[i], vb1 = b1[i];
  float4 r;
  r.x = p0 * (va0.x + vb0.x) + p1 * (va1.x + vb1.x);
  r.y = p0 * (va0.y + vb0.y) + p1 * (va1.y + vb1.y);
  r.z = p0 * (va0.z + vb0.z) + p1 * (va1.z + vb1.z);
  r.w = p0 * (va0.w + vb0.w) + p1 * (va1.w + vb1.w);
  o[i] = r;
}

extern "C" void kernel_launch(void* const* d_in, const int* in_sizes, int n_in,
                              void* d_out, int out_size, void* d_ws, size_t ws_size,
                              hipStream_t stream) {
  const float* x      = (const float*)d_in[0];
  const float* gate_w = (const float*)d_in[1];
  const float* gate_b = (const float*)d_in[2];
  const float* ln1_w  = (const float*)d_in[3];
  const float* ln1_b  = (const float*)d_in[4];
  const float* ipw    = (const float*)d_in[5];
  const float* ipb    = (const float*)d_in[6];
  const float* opw    = (const float*)d_in[7];
  const float* opb    = (const float*)d_in[8];
  const float* ln2_w  = (const float*)d_in[9];
  const float* ln2_b  = (const float*)d_in[10];
  const float* w1     = (const float*)d_in[11];
  const float* b1     = (const float*)d_in[12];
  const float* w2     = (const float*)d_in[13];
  const float* b2     = (const float*)d_in[14];
  float* out = (float*)d_out;

  const int SZ_IP = NEXP * 3 * E_DIM * E_DIM;
  const int SZ_OP = NEXP * E_DIM * E_DIM;
  const int SZ_W1 = NEXP * HID_D * E_DIM;
  const int SZ_W2 = NEXP * E_DIM * HID_D;
  const int NROW = NROW_;

  char* ws = (char*)d_ws;
  size_t off = 0;
  auto carve = [&](size_t bytes) -> void* {
    void* p = ws + off;
    off += (bytes + 255) & ~(size_t)255;
    return p;
  };
  __hip_bfloat16* ipw_bf = (__hip_bfloat16*)carve((size_t)SZ_IP * 2);
  __hip_bfloat16* opw_bf = (__hip_bfloat16*)carve((size_t)SZ_OP * 2);
  __hip_bfloat16* w1_bf  = (__hip_bfloat16*)carve((size_t)SZ_W1 * 2);
  __hip_bfloat16* w2_bf  = (__hip_bfloat16*)carve((size_t)SZ_W2 * 2);
  __hip_bfloat16* h_bf   = (__hip_bfloat16*)carve((size_t)NROW * E_DIM * 2);
  __hip_bfloat16* q_bf   = (__hip_bfloat16*)carve((size_t)NROW * E_DIM * 2);
  __hip_bfloat16* k_bf   = (__hip_bfloat16*)carve((size_t)NROW * E_DIM * 2);
  __hip_bfloat16* v_bf   = (__hip_bfloat16*)carve((size_t)NROW * E_DIM * 2);
  __hip_bfloat16* o_bf   = (__hip_bfloat16*)carve((size_t)NROW * E_DIM * 2);
  __hip_bfloat16* h2_bf  = (__hip_bfloat16*)carve((size_t)NROW * E_DIM * 2);
  __hip_bfloat16* mid_bf = (__hip_bfloat16*)carve((size_t)NROW * HID_D * 2);
  short* vT     = (short*)carve((size_t)E_DIM * VT_STRIDE * 2);
  float* x1     = (float*)carve((size_t)NROW * E_DIM * 4);
  int* token_e  = (int*)carve((size_t)NROW * 4);
  float* token_p= (float*)carve((size_t)NROW * 4);
  int* perm     = (int*)carve((size_t)NROW * 4);
  int* rowg     = (int*)carve((size_t)NROW * 4);
  int* pmap     = (int*)carve((size_t)NROW * 4);
  int* invrow   = (int*)carve((size_t)NROW * 4);
  int* offs     = (int*)carve(9 * 4);
  int* padoffs  = (int*)carve(9 * 4);
  // y1[4096][512] fp32 (8 MB) aliases h_bf+q_bf; y2 aliases k_bf+v_bf (all dead by MODE 3)
  float* ybuf  = (float*)h_bf;
  float* ybuf2 = (float*)k_bf;

  cvt_weights<<<SZ_W1 / 4 / 256, 256, 0, stream>>>(ipw, opw, w1, w2, ipw_bf, opw_bf,
                                                   w1_bf, w2_bf, SZ_IP, SZ_OP, SZ_W1, SZ_W2);
  gate_kernel<<<T_TOK / 4, 256, 0, stream>>>(x, gate_w, gate_b, token_e, token_p);
  route_kernel<<<8, 256, 0, stream>>>(token_e, perm, rowg, pmap, invrow, offs, padoffs);
  ln_kernel<<<NROW / 4, 256, 0, stream>>>(x, perm, rowg, ln1_w, ln1_b, h_bf);
  gemm_mfma<0><<<8 * 24 * 32, 256, 0, stream>>>((const short*)h_bf, (const short*)ipw_bf,
      ipb, offs, perm, nullptr, q_bf, k_bf, v_bf, nullptr, nullptr);
  transpose_v<<<dim3(NROW / 64, E_DIM / 64), 256, 0, stream>>>((const short*)v_bf, pmap,
      offs, padoffs, vT);
  attn_mfma<<<8 * 8 * 32, 256, 0, stream>>>((const short*)q_bf, (const short*)k_bf,
      vT, offs, padoffs, o_bf);
  gemm_mfma<1><<<8 * 8 * 32, 256, 0, stream>>>((const short*)o_bf, (const short*)opw_bf,
      opb, offs, perm, x, nullptr, nullptr, nullptr, x1, nullptr);
  ln_kernel<<<NROW / 4, 256, 0, stream>>>(x1, nullptr, rowg, ln2_w, ln2_b, h2_bf);
  gemm_mfma<2><<<8 * 32 * 32, 256, 0, stream>>>((const short*)h2_bf, (const short*)w1_bf,
      b1, offs, perm, nullptr, mid_bf, nullptr, nullptr, nullptr, nullptr);
  gemm_mfma<3><<<8 * 2 * 8 * 32, 256, 0, stream>>>((const short*)mid_bf, (const short*)w2_bf,
      b2, offs, perm, x1, nullptr, nullptr, nullptr, ybuf, ybuf2);
  combine_kernel<<<T_TOK, 128, 0, stream>>>(ybuf, ybuf2, invrow, token_p, out);
  (void)in_sizes; (void)n_in; (void)ws_size;
}

// Round 14
// 174.153 us; speedup vs baseline: 1.1134x; 1.0028x over previous
//
#include <hip/hip_runtime.h>
#include <hip/hip_bf16.h>

#define T_TOK 2048
#define E_DIM 512
#define NHEAD 8
#define DHEAD 64
#define HID_D 2048
#define NEXP 4
#define NROW_ (2 * T_TOK)
#define VT_STRIDE 4608
#define NB_CVT 4096   // SZ_W1 / 4 / 256

typedef short short8 __attribute__((ext_vector_type(8)));
typedef float floatx4 __attribute__((ext_vector_type(4)));

__device__ __forceinline__ void gld16(const void* g, void* l) {
  __builtin_amdgcn_global_load_lds((const __attribute__((address_space(1))) void*)g,
                                   (__attribute__((address_space(3))) void*)l, 16, 0, 0);
}

__device__ inline float wave_sum(float v) {
  for (int off = 32; off > 0; off >>= 1) v += __shfl_xor(v, off);
  return v;
}

__device__ __forceinline__ unsigned pack_bf2(float a, float b) {
  __hip_bfloat16 ha = __float2bfloat16(a), hb = __float2bfloat16(b);
  unsigned ua = *(unsigned short*)&ha, ub = *(unsigned short*)&hb;
  return ua | (ub << 16);
}

__device__ __forceinline__ void cvt4(const float* __restrict__ s, __hip_bfloat16* __restrict__ d,
                                     int i4, int n) {
  if (i4 < n) {
    float4 v = *reinterpret_cast<const float4*>(s + i4);
    __hip_bfloat16 tmp[4] = {__float2bfloat16(v.x), __float2bfloat16(v.y),
                             __float2bfloat16(v.z), __float2bfloat16(v.w)};
    *reinterpret_cast<ushort4*>(d + i4) = *reinterpret_cast<const ushort4*>(tmp);
  }
}

// fused: weight fp32->bf16 conversion (blocks 0..NB_CVT-1) + gate top-2 (blocks NB_CVT..)
__global__ void cvt_gate_kernel(const float* __restrict__ s0, const float* __restrict__ s1,
                                const float* __restrict__ s2, const float* __restrict__ s3,
                                __hip_bfloat16* d0, __hip_bfloat16* d1,
                                __hip_bfloat16* d2, __hip_bfloat16* d3,
                                int n0, int n1, int n2, int n3,
                                const float* __restrict__ x, const float* __restrict__ gw,
                                const float* __restrict__ gb, int* token_e, float* token_p) {
  int b = blockIdx.x;
  if (b < NB_CVT) {
    int i4 = (b * 256 + threadIdx.x) * 4;
    cvt4(s0, d0, i4, n0);
    cvt4(s1, d1, i4, n1);
    cvt4(s2, d2, i4, n2);
    cvt4(s3, d3, i4, n3);
    return;
  }
  int wid = threadIdx.x >> 6, lane = threadIdx.x & 63;
  int t = (b - NB_CVT) * 4 + wid;
  const float4* xr = (const float4*)(x + (size_t)t * E_DIM);
  float4 u0 = xr[lane * 2], u1 = xr[lane * 2 + 1];
  float a[4];
#pragma unroll
  for (int e = 0; e < 4; e++) {
    const float4* wr = (const float4*)(gw + e * E_DIM);
    float4 w0 = wr[lane * 2], w1 = wr[lane * 2 + 1];
    a[e] = u0.x * w0.x + u0.y * w0.y + u0.z * w0.z + u0.w * w0.w +
           u1.x * w1.x + u1.y * w1.y + u1.z * w1.z + u1.w * w1.w;
  }
  a[0] = wave_sum(a[0]); a[1] = wave_sum(a[1]);
  a[2] = wave_sum(a[2]); a[3] = wave_sum(a[3]);
  if (lane == 0) {
    float lg[4] = {a[0] + gb[0], a[1] + gb[1], a[2] + gb[2], a[3] + gb[3]};
    int i0 = 0;
    for (int e = 1; e < 4; e++) if (lg[e] > lg[i0]) i0 = e;   // strict > : lowest idx on tie
    int i1 = -1;
    for (int e = 0; e < 4; e++) {
      if (e == i0) continue;
      if (i1 < 0 || lg[e] > lg[i1]) i1 = e;
    }
    float e1 = __expf(lg[i1] - lg[i0]);
    float inv = 1.f / (1.f + e1);
    token_e[t] = i0; token_e[T_TOK + t] = i1;
    token_p[t] = inv; token_p[T_TOK + t] = e1 * inv;
  }
}

// fused count + prefix + stable compaction (8 blocks; each recomputes all counts)
__global__ void route_kernel(const int* __restrict__ token_e, int* perm, int* rowg,
                             int* pmap, int* invrow, int* offs_out, int* padoffs_out) {
  int g = blockIdx.x, kk = g >> 2, e = g & 3;
  int tid = threadIdx.x, wid = tid >> 6, lane = tid & 63;
  __shared__ int cnt_s[8][4];
  for (int gg = 0; gg < 8; gg++) {
    int kk2 = gg >> 2, e2 = gg & 3;
    int c = 0;
    for (int t = tid; t < T_TOK; t += 256) c += (token_e[kk2 * T_TOK + t] == e2);
    for (int off = 32; off; off >>= 1) c += __shfl_xor(c, off);
    if (lane == 0) cnt_s[gg][wid] = c;
  }
  __syncthreads();
  int offs[9], padoffs[9];
  offs[0] = 0; padoffs[0] = 0;
  for (int gg = 0; gg < 8; gg++) {
    int c = cnt_s[gg][0] + cnt_s[gg][1] + cnt_s[gg][2] + cnt_s[gg][3];
    offs[gg + 1] = offs[gg] + c;
    padoffs[gg + 1] = padoffs[gg] + ((c + 63) & ~63);
  }
  if (g == 0 && tid < 9) { offs_out[tid] = offs[tid]; padoffs_out[tid] = padoffs[tid]; }
  int og = offs[g], pg = padoffs[g];
  __shared__ int wcnt[4];
  __shared__ int base;
  if (tid == 0) base = 0;
  __syncthreads();
  for (int t0 = 0; t0 < T_TOK; t0 += 256) {
    int t = t0 + tid;
    bool pred = token_e[kk * T_TOK + t] == e;
    unsigned long long mask = __ballot(pred);
    int rank = __popcll(mask & ((1ull << lane) - 1ull));
    if (lane == 0) wcnt[wid] = __popcll(mask);
    __syncthreads();
    int woff = 0;
    for (int i = 0; i < wid; i++) woff += wcnt[i];
    if (pred) {
      int row = og + base + woff + rank;
      perm[row] = t;
      rowg[row] = g;
      pmap[row] = pg + (row - og);
      invrow[kk * T_TOK + t] = row;
    }
    __syncthreads();
    if (tid == 0) base += wcnt[0] + wcnt[1] + wcnt[2] + wcnt[3];
    __syncthreads();
  }
}

// one wave per row: LayerNorm -> bf16, float4 loads (lane owns 8 contiguous elems).
// perm==nullptr: src row-indexed.
__global__ void ln_kernel(const float* __restrict__ src, const int* __restrict__ perm,
                          const int* __restrict__ rowg, const float* __restrict__ lnw,
                          const float* __restrict__ lnb, __hip_bfloat16* __restrict__ dst) {
  int wid = threadIdx.x >> 6, lane = threadIdx.x & 63;
  int row = blockIdx.x * 4 + wid;
  int e = rowg[row] & 3;
  const float4* xr = (const float4*)(src + (size_t)(perm ? perm[row] : row) * E_DIM);
  float4 u0 = xr[lane * 2], u1 = xr[lane * 2 + 1];
  float s = u0.x + u0.y + u0.z + u0.w + u1.x + u1.y + u1.z + u1.w;
  s = wave_sum(s);
  float mu = s * (1.f / 512.f);
  float v[8] = {u0.x - mu, u0.y - mu, u0.z - mu, u0.w - mu,
                u1.x - mu, u1.y - mu, u1.z - mu, u1.w - mu};
  float q = 0;
#pragma unroll
  for (int i = 0; i < 8; i++) q += v[i] * v[i];
  q = wave_sum(q);
  float rstd = rsqrtf(q * (1.f / 512.f) + 1e-5f);
  const float4* wr = (const float4*)(lnw + e * E_DIM);
  const float4* br = (const float4*)(lnb + e * E_DIM);
  float4 w0 = wr[lane * 2], w1 = wr[lane * 2 + 1];
  float4 b0 = br[lane * 2], b1 = br[lane * 2 + 1];
  float wv[8] = {w0.x, w0.y, w0.z, w0.w, w1.x, w1.y, w1.z, w1.w};
  float bv[8] = {b0.x, b0.y, b0.z, b0.w, b1.x, b1.y, b1.z, b1.w};
  union { unsigned u[4]; short8 s8; } o;
#pragma unroll
  for (int i = 0; i < 4; i++)
    o.u[i] = pack_bf2(v[2 * i] * rstd * wv[2 * i] + bv[2 * i],
                      v[2 * i + 1] * rstd * wv[2 * i + 1] + bv[2 * i + 1]);
  *reinterpret_cast<short8*>(dst + (size_t)row * E_DIM + lane * 8) = o.s8;
}

// tiled transpose: v[4096][512] -> vT[512][VT_STRIDE] at padded columns pmap[row];
// blocks with blockIdx.x < 8 also zero group blockIdx.x's padded gap for their d-range
__global__ void transpose_v(const short* __restrict__ v, const int* __restrict__ pmap,
                            const int* __restrict__ offs, const int* __restrict__ padoffs,
                            short* __restrict__ vT) {
  __shared__ short tile[64][65];
  int r0 = blockIdx.x * 64, c0 = blockIdx.y * 64;
  int tc = threadIdx.x & 63, tr4 = threadIdx.x >> 6;
  for (int i = 0; i < 64; i += 4)
    tile[tr4 + i][tc] = v[(size_t)(r0 + tr4 + i) * E_DIM + c0 + tc];
  __syncthreads();
  int pcol = pmap[r0 + tc];
  for (int i = 0; i < 64; i += 4)
    vT[(size_t)(c0 + tr4 + i) * VT_STRIDE + pcol] = tile[tc][tr4 + i];
  // fused gap zeroing (masked P=0 must hit finite V)
  int gg = blockIdx.x;
  if (gg < 8) {
    int cnt = offs[gg + 1] - offs[gg];
    int gap = (padoffs[gg + 1] - padoffs[gg]) - cnt;
    int colbase = padoffs[gg] + cnt;
    if (gap > 0) {
      for (int dl = 0; dl < 64; dl += 4) {
        int d = c0 + dl + tr4;
        if (tc < gap) vT[(size_t)d * VT_STRIDE + colbase + tc] = 0;
      }
    }
  }
}

// flash attention, swapped-QK, zero-shuffle PV, defer-max, KVBLK=64,
// triple-buffered LDS with counted vmcnt, setprio around MFMA.
// 1-D grid, XCD-remapped: g = d&7 (one group per XCD), then h, q-block.
__global__ __launch_bounds__(256) void attn_mfma(
    const short* __restrict__ qb, const short* __restrict__ kb,
    const short* __restrict__ vT, const int* __restrict__ offs,
    const int* __restrict__ padoffs, __hip_bfloat16* __restrict__ ob) {
  int d0 = blockIdx.x;
  int g = d0 & 7;
  int rem = d0 >> 3;
  int h = rem >> 5;
  int qblk = rem & 31;
  int sbeg = offs[g], rend = offs[g + 1];
  int q0 = sbeg + qblk * 64;
  if (q0 >= rend) return;
  int G = rend - sbeg;
  int pg = padoffs[g];
  int tid = threadIdx.x, wid = tid >> 6, lane = tid & 63;
  int fr = lane & 15, lg = lane >> 4;
  int qw = q0 + wid * 16;

  __shared__ short Kt[3][64 * 64];   // [key][ch], 128B rows, swz ((key&7)<<4)  (8KB/buf)
  __shared__ short Vt[3][64 * 64];   // [d][key],  128B rows, swz ((d&7)<<4)    (8KB/buf)

  int arow = qw + fr; if (arow > rend - 1) arow = rend - 1;
  const short* qp = qb + (size_t)arow * E_DIM + h * DHEAD;
  short8 qf0 = *reinterpret_cast<const short8*>(qp + lg * 8);
  short8 qf1 = *reinterpret_cast<const short8*>(qp + 32 + lg * 8);

  // staging geometry: 2 chunks x 4KB per buffer; linear dest, pre-swizzled source
  int st_row[2], st_src[2];
  int wb = wid << 9;                          // wave-uniform chunk base (shorts)
  for (int c = 0; c < 2; c++) {
    int off = c * 4096 + tid * 16;
    int row = off >> 7, inner = off & 127;
    st_row[c] = row;
    st_src[c] = (inner ^ ((row & 7) << 4)) >> 1;
  }

  auto stage = [&](int buf, int kbase) {
#pragma unroll
    for (int c = 0; c < 2; c++) {
      int gr = sbeg + kbase + st_row[c]; if (gr > NROW_ - 1) gr = NROW_ - 1;
      gld16(kb + (size_t)gr * E_DIM + h * DHEAD + st_src[c], &Kt[buf][c * 2048 + wb]);
      gld16(vT + (size_t)(h * DHEAD + st_row[c]) * VT_STRIDE + pg + kbase + st_src[c],
            &Vt[buf][c * 2048 + wb]);
    }
  };

  floatx4 acc[4] = {};
  float m_r = -1e30f, l_r = 0.f;
  int nt = (G + 63) >> 6;

  stage(0, 0);
  if (nt > 1) stage(1, 64);
  if (nt > 1) asm volatile("s_waitcnt vmcnt(4)" ::: "memory");
  else        asm volatile("s_waitcnt vmcnt(0)" ::: "memory");
  __builtin_amdgcn_s_barrier();
  __builtin_amdgcn_sched_barrier(0);

  int bcur = 0;
  for (int t = 0; t < nt; ++t) {
    int kbase = t * 64;
    int b2 = bcur + 2; if (b2 >= 3) b2 -= 3;
    if (t + 2 < nt) stage(b2, kbase + 128);
    const char* Kb = (const char*)&Kt[bcur][0];
    const char* Vb = (const char*)&Vt[bcur][0];

    // QK^T: 4 key-subtiles of 16 rows
    floatx4 s[4];
    __builtin_amdgcn_s_setprio(1);
#pragma unroll
    for (int c = 0; c < 4; c++) {
      int rc = c * 16 + fr;
      int sx = (rc & 7) << 4;
      short8 kf0 = *reinterpret_cast<const short8*>(Kb + rc * 128 + ((lg * 16) ^ sx));
      short8 kf1 = *reinterpret_cast<const short8*>(Kb + rc * 128 + ((64 + lg * 16) ^ sx));
      floatx4 z = {};
      z = __builtin_amdgcn_mfma_f32_16x16x32_bf16(kf0, qf0, z, 0, 0, 0);
      z = __builtin_amdgcn_mfma_f32_16x16x32_bf16(kf1, qf1, z, 0, 0, 0);
      s[c] = z;
    }
    __builtin_amdgcn_s_setprio(0);

    // lane (q=fr, lg) holds keys kbase + c*16 + 4lg + j
    float sv[16];
    float mloc = -1e30f;
#pragma unroll
    for (int c = 0; c < 4; c++)
#pragma unroll
      for (int j = 0; j < 4; j++) {
        int k0 = kbase + c * 16 + lg * 4 + j;
        float v = (k0 < G) ? s[c][j] * 0.125f : -1e30f;
        sv[c * 4 + j] = v;
        mloc = fmaxf(mloc, v);
      }
    mloc = fmaxf(mloc, __shfl_xor(mloc, 16));
    mloc = fmaxf(mloc, __shfl_xor(mloc, 32));
    // defer-max: rescale only when the running max grows by > 8
    if (__any(mloc > m_r + 8.f)) {
      float mn = fmaxf(m_r, mloc);
      float corr = __expf(m_r - mn);
      m_r = mn;
      l_r *= corr;
      float cq0 = __shfl(corr, lg * 4 + 0), cq1 = __shfl(corr, lg * 4 + 1);
      float cq2 = __shfl(corr, lg * 4 + 2), cq3 = __shfl(corr, lg * 4 + 3);
#pragma unroll
      for (int db = 0; db < 4; db++) {
        acc[db][0] *= cq0; acc[db][1] *= cq1; acc[db][2] *= cq2; acc[db][3] *= cq3;
      }
    }
    float p[16], sl = 0.f;
#pragma unroll
    for (int i = 0; i < 16; i++) { p[i] = __expf(sv[i] - m_r); sl += p[i]; }
    sl += __shfl_xor(sl, 16);
    sl += __shfl_xor(sl, 32);
    l_r += sl;

    // zero-shuffle PV: per 16-key subtile c, A slots 0-1 = P(keys c*16+4lg+j), rest 0
    union { unsigned u[4]; short8 s8; } pa[4];
#pragma unroll
    for (int c = 0; c < 4; c++) {
      pa[c].u[0] = pack_bf2(p[c * 4 + 0], p[c * 4 + 1]);
      pa[c].u[1] = pack_bf2(p[c * 4 + 2], p[c * 4 + 3]);
      pa[c].u[2] = 0; pa[c].u[3] = 0;
    }
    __builtin_amdgcn_s_setprio(1);
#pragma unroll
    for (int db = 0; db < 4; db++) {
      int dd = db * 16 + fr;
      int sx = (dd & 7) << 4;
#pragma unroll
      for (int c = 0; c < 4; c++) {
        uint2 w = *reinterpret_cast<const uint2*>(Vb + ((dd * 128 + c * 32 + lg * 8) ^ sx));
        union { unsigned u[4]; short8 s8; } bv;
        bv.u[0] = w.x; bv.u[1] = w.y; bv.u[2] = 0; bv.u[3] = 0;
        acc[db] = __builtin_amdgcn_mfma_f32_16x16x32_bf16(pa[c].s8, bv.s8, acc[db], 0, 0, 0);
      }
    }
    __builtin_amdgcn_s_setprio(0);

    if (t + 1 < nt) {
      if (t + 2 < nt) asm volatile("s_waitcnt vmcnt(4)" ::: "memory");
      else            asm volatile("s_waitcnt vmcnt(0)" ::: "memory");
      asm volatile("s_waitcnt lgkmcnt(0)" ::: "memory");
      __builtin_amdgcn_s_barrier();
      __builtin_amdgcn_sched_barrier(0);
    }
    bcur = bcur + 1; if (bcur == 3) bcur = 0;
  }

  float lq0 = __shfl(l_r, lg * 4 + 0), lq1 = __shfl(l_r, lg * 4 + 1);
  float lq2 = __shfl(l_r, lg * 4 + 2), lq3 = __shfl(l_r, lg * 4 + 3);
  float lq[4] = {lq0, lq1, lq2, lq3};
#pragma unroll
  for (int db = 0; db < 4; db++)
#pragma unroll
    for (int j = 0; j < 4; j++) {
      int row = qw + lg * 4 + j;
      if (row < rend)
        ob[(size_t)row * E_DIM + h * DHEAD + db * 16 + fr] = __float2bfloat16(acc[db][j] / lq[j]);
    }
}

// 64x64-tile MFMA GEMM, triple-buffered LDS, depth-2 prefetch, counted vmcnt,
// 1-D XCD-remapped grid (one group per XCD).
// MODE 0: QKV -> q/k/v bf16 split     (K=512,  N=1536)
// MODE 1: out-proj + x residual -> x1 (K=512,  N=512)
// MODE 2: MLP1 + exact GELU -> bf16   (K=512,  N=2048)
// MODE 3: MLP2 split-K x2 -> y1 (=val+bias+resid) / y2 (=val) (K=2048, N=512)
template <int MODE>
__global__ __launch_bounds__(256) void gemm_mfma(
    const short* __restrict__ A, const short* __restrict__ Wb,
    const float* __restrict__ bias, const int* __restrict__ offs,
    const int* __restrict__ perm, const float* __restrict__ resid,
    __hip_bfloat16* __restrict__ bq, __hip_bfloat16* __restrict__ bk,
    __hip_bfloat16* __restrict__ bv, float* __restrict__ outf,
    float* __restrict__ outf2) {
  constexpr int K = (MODE == 3) ? HID_D : E_DIM;
  constexpr int N = (MODE == 0) ? 3 * E_DIM : (MODE == 2) ? HID_D : E_DIM;
  constexpr bool SPLIT = (MODE == 3);
  constexpr int KLEN = SPLIT ? K / 2 : K;
  constexpr int NKSTEP = KLEN / 64;
  constexpr int NXB = 32;
  __shared__ short Abuf[3][4096];   // [buf][64 rows][64 k], 128B rows, linear
  __shared__ short Bbuf[3][4096];

  int d = blockIdx.x;
  int g = d & 7;                    // one group per XCD: L2-resident panels
  int rem = d >> 3;
  int ksel = 0;
  if constexpr (SPLIT) { ksel = rem & 1; rem >>= 1; }
  int yb = rem / NXB, xb = rem % NXB;   // xb innermost: same-panel blocks adjacent
  int e = g & 3;
  int rbeg = offs[g], rend = offs[g + 1];
  int row0 = rbeg + xb * 64;
  if (row0 >= rend) return;
  int col0 = yb * 64;
  int kbeg = ksel * KLEN;
  int tid = threadIdx.x;
  int wid = tid >> 6, lane = tid & 63;
  int wm = wid >> 1, wn = wid & 1;
  int fr = lane & 15, lg = lane >> 4;
  const short* wbase = Wb + (size_t)e * N * K;

  int st_row[2], st_src[2], st_arow[2];
  int wavebase = wid << 9;
  for (int c = 0; c < 2; c++) {
    int off = c * 4096 + tid * 16;
    int trow = off >> 7;
    int inner = off & 127;
    st_row[c] = trow;
    st_src[c] = (inner ^ ((trow & 7) << 4)) >> 1;
    int ga = row0 + trow;
    st_arow[c] = ga < rend ? ga : rend - 1;
  }

  auto stage = [&](int buf, int kb) {
#pragma unroll
    for (int c = 0; c < 2; c++) {
      gld16(A + (size_t)st_arow[c] * K + kb + st_src[c], &Abuf[buf][c * 2048 + wavebase]);
      gld16(wbase + (size_t)(col0 + st_row[c]) * K + kb + st_src[c],
            &Bbuf[buf][c * 2048 + wavebase]);
    }
  };

  floatx4 acc[2][2] = {};
  stage(0, kbeg);
  stage(1, kbeg + 64);
  asm volatile("s_waitcnt vmcnt(4)" ::: "memory");   // tile0 landed; tile1 in flight
  __builtin_amdgcn_s_barrier();
  __builtin_amdgcn_sched_barrier(0);

  int bcur = 0;
  for (int t = 0; t < NKSTEP; ++t) {
    int b2 = bcur + 2; if (b2 >= 3) b2 -= 3;
    if (t + 2 < NKSTEP) stage(b2, kbeg + (t + 2) * 64);
    const char* Ab = (const char*)&Abuf[bcur][0];
    const char* Bb = (const char*)&Bbuf[bcur][0];
    short8 af[2][2], bf8[2][2];
#pragma unroll
    for (int mi = 0; mi < 2; mi++)
#pragma unroll
      for (int ks = 0; ks < 2; ks++) {
        int row = wm * 32 + mi * 16 + fr;
        int cb = ks * 64 + lg * 16;
        af[mi][ks] = *reinterpret_cast<const short8*>(Ab + row * 128 + (cb ^ ((row & 7) << 4)));
      }
#pragma unroll
    for (int ni = 0; ni < 2; ni++)
#pragma unroll
      for (int ks = 0; ks < 2; ks++) {
        int row = wn * 32 + ni * 16 + fr;
        int cb = ks * 64 + lg * 16;
        bf8[ni][ks] = *reinterpret_cast<const short8*>(Bb + row * 128 + (cb ^ ((row & 7) << 4)));
      }
#pragma unroll
    for (int mi = 0; mi < 2; mi++)
#pragma unroll
      for (int ni = 0; ni < 2; ni++) {
        acc[mi][ni] = __builtin_amdgcn_mfma_f32_16x16x32_bf16(af[mi][0], bf8[ni][0], acc[mi][ni], 0, 0, 0);
        acc[mi][ni] = __builtin_amdgcn_mfma_f32_16x16x32_bf16(af[mi][1], bf8[ni][1], acc[mi][ni], 0, 0, 0);
      }
    if (t + 1 < NKSTEP) {
      if (t + 2 < NKSTEP) asm volatile("s_waitcnt vmcnt(4)" ::: "memory");  // next tile landed
      else                asm volatile("s_waitcnt vmcnt(0)" ::: "memory");
      asm volatile("s_waitcnt lgkmcnt(0)" ::: "memory");
      __builtin_amdgcn_s_barrier();
      __builtin_amdgcn_sched_barrier(0);
    }
    bcur = (bcur + 1 == 3) ? 0 : bcur + 1;
  }

  for (int mi = 0; mi < 2; mi++)
    for (int ni = 0; ni < 2; ni++)
      for (int j = 0; j < 4; j++) {
        int row = row0 + wm * 32 + mi * 16 + lg * 4 + j;
        if (row >= rend) continue;
        int col = col0 + wn * 32 + ni * 16 + fr;
        float val = acc[mi][ni][j];
        if constexpr (MODE != 3) val += bias[e * N + col];
        if constexpr (MODE == 0) {
          if (col < E_DIM) bq[(size_t)row * E_DIM + col] = __float2bfloat16(val);
          else if (col < 2 * E_DIM) bk[(size_t)row * E_DIM + col - E_DIM] = __float2bfloat16(val);
          else bv[(size_t)row * E_DIM + col - 2 * E_DIM] = __float2bfloat16(val);
        } else if constexpr (MODE == 1) {
          int t = perm[row];
          outf[(size_t)row * E_DIM + col] = val + resid[(size_t)t * E_DIM + col];
        } else if constexpr (MODE == 2) {
          float gl = 0.5f * val * (1.f + erff(val * 0.70710678118654752f));
          bq[(size_t)row * HID_D + col] = __float2bfloat16(gl);
        } else {
          if (ksel == 0) {
            val += bias[e * N + col] + resid[(size_t)row * E_DIM + col];
            outf[(size_t)row * E_DIM + col] = val;
          } else {
            outf2[(size_t)row * E_DIM + col] = val;
          }
        }
      }
}

// out[t] = sum_kk p_kk * (y1[row_kk] + y2[row_kk])   (fixed order: deterministic)
__global__ void combine_kernel(const float* __restrict__ y1, const float* __restrict__ y2,
                               const int* __restrict__ invrow,
                               const float* __restrict__ token_p, float* __restrict__ out) {
  int t = blockIdx.x;
  int r0 = invrow[t], r1 = invrow[T_TOK + t];
  float p0 = token_p[t], p1 = token_p[T_TOK + t];
  const float4* a0 = (const float4*)(y1 + (size_t)r0 * E_DIM);
  const float4* b0 = (const float4*)(y2 + (size_t)r0 * E_DIM);
  const float4* a1 = (const float4*)(y1 + (size_t)r1 * E_DIM);
  const float4* b1 = (const float4*)(y2 + (size_t)r1 * E_DIM);
  float4* o = (float4*)(out + (size_t)t * E_DIM);
  int i = threadIdx.x;
  float4 va0 = a0[i], vb0 = b0[i], va1 = a1[i], vb1 = b1[i];
  float4 r;
  r.x = p0 * (va0.x + vb0.x) + p1 * (va1.x + vb1.x);
  r.y = p0 * (va0.y + vb0.y) + p1 * (va1.y + vb1.y);
  r.z = p0 * (va0.z + vb0.z) + p1 * (va1.z + vb1.z);
  r.w = p0 * (va0.w + vb0.w) + p1 * (va1.w + vb1.w);
  o[i] = r;
}

extern "C" void kernel_launch(void* const* d_in, const int* in_sizes, int n_in,
                              void* d_out, int out_size, void* d_ws, size_t ws_size,
                              hipStream_t stream) {
  const float* x      = (const float*)d_in[0];
  const float* gate_w = (const float*)d_in[1];
  const float* gate_b = (const float*)d_in[2];
  const float* ln1_w  = (const float*)d_in[3];
  const float* ln1_b  = (const float*)d_in[4];
  const float* ipw    = (const float*)d_in[5];
  const float* ipb    = (const float*)d_in[6];
  const float* opw    = (const float*)d_in[7];
  const float* opb    = (const float*)d_in[8];
  const float* ln2_w  = (const float*)d_in[9];
  const float* ln2_b  = (const float*)d_in[10];
  const float* w1     = (const float*)d_in[11];
  const float* b1     = (const float*)d_in[12];
  const float* w2     = (const float*)d_in[13];
  const float* b2     = (const float*)d_in[14];
  float* out = (float*)d_out;

  const int SZ_IP = NEXP * 3 * E_DIM * E_DIM;
  const int SZ_OP = NEXP * E_DIM * E_DIM;
  const int SZ_W1 = NEXP * HID_D * E_DIM;
  const int SZ_W2 = NEXP * E_DIM * HID_D;
  const int NROW = NROW_;

  char* ws = (char*)d_ws;
  size_t off = 0;
  auto carve = [&](size_t bytes) -> void* {
    void* p = ws + off;
    off += (bytes + 255) & ~(size_t)255;
    return p;
  };
  __hip_bfloat16* ipw_bf = (__hip_bfloat16*)carve((size_t)SZ_IP * 2);
  __hip_bfloat16* opw_bf = (__hip_bfloat16*)carve((size_t)SZ_OP * 2);
  __hip_bfloat16* w1_bf  = (__hip_bfloat16*)carve((size_t)SZ_W1 * 2);
  __hip_bfloat16* w2_bf  = (__hip_bfloat16*)carve((size_t)SZ_W2 * 2);
  __hip_bfloat16* h_bf   = (__hip_bfloat16*)carve((size_t)NROW * E_DIM * 2);
  __hip_bfloat16* q_bf   = (__hip_bfloat16*)carve((size_t)NROW * E_DIM * 2);
  __hip_bfloat16* k_bf   = (__hip_bfloat16*)carve((size_t)NROW * E_DIM * 2);
  __hip_bfloat16* v_bf   = (__hip_bfloat16*)carve((size_t)NROW * E_DIM * 2);
  __hip_bfloat16* o_bf   = (__hip_bfloat16*)carve((size_t)NROW * E_DIM * 2);
  __hip_bfloat16* h2_bf  = (__hip_bfloat16*)carve((size_t)NROW * E_DIM * 2);
  __hip_bfloat16* mid_bf = (__hip_bfloat16*)carve((size_t)NROW * HID_D * 2);
  short* vT     = (short*)carve((size_t)E_DIM * VT_STRIDE * 2);
  float* x1     = (float*)carve((size_t)NROW * E_DIM * 4);
  int* token_e  = (int*)carve((size_t)NROW * 4);
  float* token_p= (float*)carve((size_t)NROW * 4);
  int* perm     = (int*)carve((size_t)NROW * 4);
  int* rowg     = (int*)carve((size_t)NROW * 4);
  int* pmap     = (int*)carve((size_t)NROW * 4);
  int* invrow   = (int*)carve((size_t)NROW * 4);
  int* offs     = (int*)carve(9 * 4);
  int* padoffs  = (int*)carve(9 * 4);
  // y1[4096][512] fp32 (8 MB) aliases h_bf+q_bf; y2 aliases k_bf+v_bf (all dead by MODE 3)
  float* ybuf  = (float*)h_bf;
  float* ybuf2 = (float*)k_bf;

  cvt_gate_kernel<<<NB_CVT + T_TOK / 4, 256, 0, stream>>>(
      ipw, opw, w1, w2, ipw_bf, opw_bf, w1_bf, w2_bf, SZ_IP, SZ_OP, SZ_W1, SZ_W2,
      x, gate_w, gate_b, token_e, token_p);
  route_kernel<<<8, 256, 0, stream>>>(token_e, perm, rowg, pmap, invrow, offs, padoffs);
  ln_kernel<<<NROW / 4, 256, 0, stream>>>(x, perm, rowg, ln1_w, ln1_b, h_bf);
  gemm_mfma<0><<<8 * 24 * 32, 256, 0, stream>>>((const short*)h_bf, (const short*)ipw_bf,
      ipb, offs, perm, nullptr, q_bf, k_bf, v_bf, nullptr, nullptr);
  transpose_v<<<dim3(NROW / 64, E_DIM / 64), 256, 0, stream>>>((const short*)v_bf, pmap,
      offs, padoffs, vT);
  attn_mfma<<<8 * 8 * 32, 256, 0, stream>>>((const short*)q_bf, (const short*)k_bf,
      vT, offs, padoffs, o_bf);
  gemm_mfma<1><<<8 * 8 * 32, 256, 0, stream>>>((const short*)o_bf, (const short*)opw_bf,
      opb, offs, perm, x, nullptr, nullptr, nullptr, x1, nullptr);
  ln_kernel<<<NROW / 4, 256, 0, stream>>>(x1, nullptr, rowg, ln2_w, ln2_b, h2_bf);
  gemm_mfma<2><<<8 * 32 * 32, 256, 0, stream>>>((const short*)h2_bf, (const short*)w1_bf,
      b1, offs, perm, nullptr, mid_bf, nullptr, nullptr, nullptr, nullptr);
  gemm_mfma<3><<<8 * 2 * 8 * 32, 256, 0, stream>>>((const short*)mid_bf, (const short*)w2_bf,
      b2, offs, perm, x1, nullptr, nullptr, nullptr, ybuf, ybuf2);
  combine_kernel<<<T_TOK, 128, 0, stream>>>(ybuf, ybuf2, invrow, token_p, out);
  (void)in_sizes; (void)n_in; (void)ws_size;
}